// Round 11
// baseline (661.622 us; speedup 1.0000x reference)
//
#include <hip/hip_runtime.h>
#include <hip/hip_bf16.h>

#define NN 100000
#define NE 600000

typedef __bf16 bf16x8 __attribute__((ext_vector_type(8)));
typedef float  f32x4  __attribute__((ext_vector_type(4)));

__device__ __forceinline__ float dot4(float4 a, float4 b){
  return a.x*b.x + a.y*b.y + a.z*b.z + a.w*b.w;
}

// ---------------- CSR build (dst-grouped) ----------------
__global__ void count_edges(const int* __restrict__ dst, int* __restrict__ cnt){
  int e = blockIdx.x*256 + threadIdx.x;
  if (e < NE){
    unsigned d = (unsigned)dst[e];
    if (d < NN) atomicAdd(&cnt[d], 1);
  }
}

__global__ void scan1(const int* __restrict__ cnt, int* __restrict__ offs, int* __restrict__ bsum){
  __shared__ int sh[256];
  const int tid = threadIdx.x;
  const int base = blockIdx.x*2048 + tid*8;
  int pre[8]; int s = 0;
  #pragma unroll
  for (int j=0;j<8;j++){
    int idx = base + j;
    int v = (idx < NN) ? cnt[idx] : 0;
    pre[j] = s; s += v;
  }
  sh[tid] = s;
  __syncthreads();
  for (int d=1; d<256; d<<=1){
    int t = (tid >= d) ? sh[tid-d] : 0;
    __syncthreads();
    sh[tid] += t;
    __syncthreads();
  }
  int off = (tid > 0) ? sh[tid-1] : 0;
  #pragma unroll
  for (int j=0;j<8;j++){
    int idx = base + j;
    if (idx < NN) offs[idx] = off + pre[j];
  }
  if (tid == 255) bsum[blockIdx.x] = sh[255];
}

__global__ void scan2(int* __restrict__ bsum){
  if (threadIdx.x == 0){
    int s = 0;
    for (int i=0;i<49;i++){ int t = bsum[i]; bsum[i] = s; s += t; }
  }
}

__global__ void scan3(int* __restrict__ offs, const int* __restrict__ bsum, int* __restrict__ cursor){
  int i = blockIdx.x*256 + threadIdx.x;
  if (i < NN){
    int v = offs[i] + bsum[i>>11];
    offs[i] = v; cursor[i] = v;
  }
  if (i == 0) offs[NN] = NE;
}

__global__ void fill_csr(const int* __restrict__ src, const int* __restrict__ dst,
                         int* __restrict__ cursor, int* __restrict__ csrsrc){
  int e = blockIdx.x*256 + threadIdx.x;
  if (e < NE){
    unsigned d = (unsigned)dst[e];
    unsigned s = (unsigned)src[e];
    if (d < NN && s < NN){
      int p = atomicAdd(&cursor[d], 1);
      csrsrc[p] = (int)s;
    }
  }
}

// ---------------- weight repack: fp32 W[K][C] -> bf16 hi/lo MFMA fragments ----
__global__ void repack_w(const float* __restrict__ Wg, const float* __restrict__ w1,
                         const float* __restrict__ w2,
                         __bf16* __restrict__ phi, __bf16* __restrict__ plo)
{
  int gid = blockIdx.x*256 + threadIdx.x;
  const float* W; int C; size_t obase; int rem;
  if (gid < 8192)      { W = Wg + (size_t)(gid/2048)*16384; C = 128; obase = (size_t)(gid/2048)*16384; rem = gid % 2048; }
  else if (gid < 10240){ W = w1; C = 128; obase = 65536; rem = gid - 8192; }
  else if (gid < 11264){ W = w2; C = 64;  obase = 81920; rem = gid - 10240; }
  else return;
  const int lane = rem & 63;
  const int tks  = rem >> 6;
  const int ks = tks & 3, t = tks >> 2;
  const int col = t*16 + (lane & 15);
  const int kb  = ks*32 + (lane >> 4)*8;
  const size_t o = obase + (size_t)rem*8;
  #pragma unroll
  for (int j=0;j<8;j++){
    float v = W[(size_t)(kb+j)*C + col];
    __bf16 hb = (__bf16)v;
    phi[o+j] = hb;
    plo[o+j] = (__bf16)(v - (float)hb);
  }
}

// ---------------- input MLP: h = relu(LN(x@w_in+b_in)) ----------------
__global__ __launch_bounds__(256) void input_mlp(const float* __restrict__ x,
    const float* __restrict__ win, const float* __restrict__ b,
    const float* __restrict__ lnw, const float* __restrict__ lnb,
    float* __restrict__ h)
{
  __shared__ float wsh[6*128];
  __shared__ float p2[4][2];
  const int tid = threadIdx.x;
  for (int i=tid;i<768;i+=256) wsh[i] = win[i];
  __syncthreads();
  const int nl = tid>>7, c = tid&127;
  const int n = blockIdx.x*2 + nl;
  float s = b[c];
  #pragma unroll
  for (int k=0;k<6;k++) s += x[n*6+k]*wsh[k*128+c];
  float sum = s, sq = s*s;
  #pragma unroll
  for (int o=32;o>=1;o>>=1){ sum += __shfl_xor(sum,o); sq += __shfl_xor(sq,o); }
  const int wv = tid>>6;
  if ((tid&63)==0){ p2[wv][0]=sum; p2[wv][1]=sq; }
  __syncthreads();
  float ts = p2[nl*2][0]+p2[nl*2+1][0];
  float tq = p2[nl*2][1]+p2[nl*2+1][1];
  float mean = ts*(1.f/128.f);
  float var  = tq*(1.f/128.f) - mean*mean;
  float y = (s-mean)*rsqrtf(var+1e-5f)*lnw[c]+lnb[c];
  h[(size_t)n*128+c] = fmaxf(y, 0.f);
}

// ---------------- MFMA split-bf16 GEMM: Y = act(LN?(X@W + b)), K=128 ----------
template<int C, bool HAS_BIAS, bool DO_LN, bool DO_RELU, bool GAT>
__global__ __launch_bounds__(256) void gemm_mfma(const float* __restrict__ X,
    const __bf16* __restrict__ Bhi, const __bf16* __restrict__ Blo,
    const float* __restrict__ bias,
    const float* __restrict__ lnw, const float* __restrict__ lnb,
    const float* __restrict__ asrc, const float* __restrict__ adst,
    float* __restrict__ Y, float* __restrict__ als, float* __restrict__ ald)
{
  constexpr int NT = C/16;
  const int tid = threadIdx.x;
  const int wid = tid >> 6, lane = tid & 63;
  const int lrow = lane & 15, lgrp = lane >> 4;
  const int m0 = (blockIdx.x*4 + wid)*16;

  // A fragments: 4 k-steps, hi/lo
  bf16x8 Ahi[4], Alo[4];
  {
    int row = m0 + lrow; if (row >= NN) row = NN-1;
    const float* Xr = X + (size_t)row*128 + lgrp*8;
    #pragma unroll
    for (int ks=0; ks<4; ks++){
      float4 u0 = *(const float4*)(Xr + ks*32);
      float4 u1 = *(const float4*)(Xr + ks*32 + 4);
      float v[8] = {u0.x,u0.y,u0.z,u0.w,u1.x,u1.y,u1.z,u1.w};
      bf16x8 h8, l8;
      #pragma unroll
      for (int j=0;j<8;j++){
        __bf16 hb = (__bf16)v[j];
        h8[j] = hb;
        l8[j] = (__bf16)(v[j] - (float)hb);
      }
      Ahi[ks] = h8; Alo[ks] = l8;
    }
  }

  f32x4 acc[NT];
  #pragma unroll
  for (int t=0;t<NT;t++){ acc[t] = (f32x4){0.f,0.f,0.f,0.f}; }

  const bf16x8* B8h = (const bf16x8*)Bhi;
  const bf16x8* B8l = (const bf16x8*)Blo;
  #pragma unroll
  for (int t=0;t<NT;t++){
    #pragma unroll
    for (int ks=0;ks<4;ks++){
      bf16x8 bh = B8h[(t*4+ks)*64 + lane];
      bf16x8 bl = B8l[(t*4+ks)*64 + lane];
      acc[t] = __builtin_amdgcn_mfma_f32_16x16x32_bf16(Ahi[ks], bh, acc[t], 0,0,0);
      acc[t] = __builtin_amdgcn_mfma_f32_16x16x32_bf16(Alo[ks], bh, acc[t], 0,0,0);
      acc[t] = __builtin_amdgcn_mfma_f32_16x16x32_bf16(Ahi[ks], bl, acc[t], 0,0,0);
    }
  }

  if constexpr (HAS_BIAS){
    #pragma unroll
    for (int t=0;t<NT;t++){
      float bv = bias[t*16 + lrow];
      #pragma unroll
      for (int i=0;i<4;i++) acc[t][i] += bv;
    }
  }

  if constexpr (GAT){
    #pragma unroll
    for (int t=0;t<NT;t++){
      float av = asrc[t*16 + lrow];
      float dv2 = adst[t*16 + lrow];
      float ps[4], pd[4];
      #pragma unroll
      for (int i=0;i<4;i++){
        int n = m0 + lgrp*4 + i;
        if (n < NN) Y[(size_t)n*C + t*16 + lrow] = acc[t][i];
        ps[i] = acc[t][i]*av; pd[i] = acc[t][i]*dv2;
      }
      #pragma unroll
      for (int off=1; off<16; off<<=1){
        #pragma unroll
        for (int i=0;i<4;i++){
          ps[i] += __shfl_xor(ps[i], off);
          pd[i] += __shfl_xor(pd[i], off);
        }
      }
      if (lrow == 0){
        #pragma unroll
        for (int i=0;i<4;i++){
          int n = m0 + lgrp*4 + i;
          if (n < NN){ als[n*8 + t] = ps[i]; ald[n*8 + t] = pd[i]; }
        }
      }
    }
  } else {
    if constexpr (DO_LN){
      float s[4] = {0,0,0,0}, q[4] = {0,0,0,0};
      #pragma unroll
      for (int t=0;t<NT;t++){
        #pragma unroll
        for (int i=0;i<4;i++){ s[i] += acc[t][i]; q[i] += acc[t][i]*acc[t][i]; }
      }
      #pragma unroll
      for (int off=1; off<16; off<<=1){
        #pragma unroll
        for (int i=0;i<4;i++){ s[i] += __shfl_xor(s[i], off); q[i] += __shfl_xor(q[i], off); }
      }
      float mean[4], rr[4];
      #pragma unroll
      for (int i=0;i<4;i++){
        mean[i] = s[i]*(1.0f/C);
        float var = q[i]*(1.0f/C) - mean[i]*mean[i];
        rr[i] = rsqrtf(var + 1e-5f);
      }
      #pragma unroll
      for (int t=0;t<NT;t++){
        float lw = lnw[t*16 + lrow], lb = lnb[t*16 + lrow];
        #pragma unroll
        for (int i=0;i<4;i++){
          float v = (acc[t][i]-mean[i])*rr[i]*lw + lb;
          if constexpr (DO_RELU) v = fmaxf(v, 0.f);
          acc[t][i] = v;
        }
      }
    } else if constexpr (DO_RELU){
      #pragma unroll
      for (int t=0;t<NT;t++){
        #pragma unroll
        for (int i=0;i<4;i++) acc[t][i] = fmaxf(acc[t][i], 0.f);
      }
    }
    #pragma unroll
    for (int t=0;t<NT;t++){
      #pragma unroll
      for (int i=0;i<4;i++){
        int n = m0 + lgrp*4 + i;
        if (n < NN) Y[(size_t)n*C + t*16 + lrow] = acc[t][i];
      }
    }
  }
}

// ---------------- per-node softmax + aggregate + LN + residual ----------------
// One wave per node; lane = channel pair (2*lane, 2*lane+1), which always share
// head h = lane>>3. Per edge: ONE float2 xw load + ONE exp chain per lane
// (halves VMEM instructions and VALU vs the (c, c+64) mapping). No max
// subtraction (logits O(1), softmax shift-invariant). No LDS, no barriers.
__global__ __launch_bounds__(256) void gat_aggregate(
    const float* __restrict__ xw, const float* __restrict__ als, const float* __restrict__ ald,
    const int* __restrict__ offs, const int* __restrict__ csrsrc,
    const float* __restrict__ bg, const float* __restrict__ lnw, const float* __restrict__ lnb,
    float* __restrict__ h)
{
  const int wv = threadIdx.x >> 6, lane = threadIdx.x & 63;
  const int n = blockIdx.x*4 + wv;
  const int hh = lane >> 3;                 // head of channels 2*lane, 2*lane+1
  const float ad = ald[n*8 + hh];

  // self-loop
  float t = als[n*8 + hh] + ad; t = t > 0.f ? t : 0.2f*t;
  float pp = __expf(t);
  float s = pp;
  float2 xv = *(const float2*)(xw + (size_t)n*128 + 2*lane);
  float acc0 = pp*xv.x, acc1 = pp*xv.y;

  const int start = offs[n], end = offs[n+1];
  int e = start;
  for (; e+4 <= end; e += 4){
    int s4[4]; float a[4]; float2 x2[4];
    #pragma unroll
    for (int j=0;j<4;j++) s4[j] = csrsrc[e+j];
    #pragma unroll
    for (int j=0;j<4;j++){
      a[j]  = als[s4[j]*8 + hh];
      x2[j] = *(const float2*)(xw + (size_t)s4[j]*128 + 2*lane);
    }
    #pragma unroll
    for (int j=0;j<4;j++){
      float u = a[j] + ad; u = u > 0.f ? u : 0.2f*u;
      float q = __expf(u);
      s += q;
      acc0 = fmaf(q, x2[j].x, acc0);
      acc1 = fmaf(q, x2[j].y, acc1);
    }
  }
  if (e+2 <= end){
    int sA = csrsrc[e], sB = csrsrc[e+1];
    float aA = als[sA*8+hh], aB = als[sB*8+hh];
    float2 xA = *(const float2*)(xw + (size_t)sA*128 + 2*lane);
    float2 xB = *(const float2*)(xw + (size_t)sB*128 + 2*lane);
    float u;
    u = aA+ad; u = u>0.f?u:0.2f*u; float qA = __expf(u);
    u = aB+ad; u = u>0.f?u:0.2f*u; float qB = __expf(u);
    s += qA+qB;
    acc0 = fmaf(qA, xA.x, fmaf(qB, xB.x, acc0));
    acc1 = fmaf(qA, xA.y, fmaf(qB, xB.y, acc1));
    e += 2;
  }
  if (e < end){
    int sA = csrsrc[e];
    float aA = als[sA*8+hh];
    float2 xA = *(const float2*)(xw + (size_t)sA*128 + 2*lane);
    float u = aA+ad; u = u>0.f?u:0.2f*u; float qA = __expf(u);
    s += qA;
    acc0 = fmaf(qA, xA.x, acc0);
    acc1 = fmaf(qA, xA.y, acc1);
  }

  float2 bgv = *(const float2*)(bg + 2*lane);
  float inv = 1.0f/s;
  float val0 = acc0*inv + bgv.x;
  float val1 = acc1*inv + bgv.y;
  // LayerNorm across 128 channels = butterfly over this wave (2 ch/lane)
  float sum = val0+val1, sq = val0*val0 + val1*val1;
  #pragma unroll
  for (int off=32; off>=1; off>>=1){ sum += __shfl_xor(sum,off); sq += __shfl_xor(sq,off); }
  float mean = sum*(1.f/128.f);
  float var  = sq*(1.f/128.f) - mean*mean;
  float rr = rsqrtf(var + 1e-5f);
  float2 lwv = *(const float2*)(lnw + 2*lane);
  float2 lbv = *(const float2*)(lnb + 2*lane);
  float y0 = (val0-mean)*rr*lwv.x + lbv.x;
  float y1 = (val1-mean)*rr*lwv.y + lbv.y;
  float2* hp = (float2*)(h + (size_t)n*128 + 2*lane);
  float2 hv = *hp;
  hv.x += fmaxf(y0, 0.f);
  hv.y += fmaxf(y1, 0.f);
  *hp = hv;
}

// ---------------- final projection: out = o2@w3 + b3 ----------------
__global__ __launch_bounds__(256) void out_proj(const float* __restrict__ o2,
    const float* __restrict__ w3, const float* __restrict__ b3, float* __restrict__ out)
{
  __shared__ float wsh[256];
  const int tid = threadIdx.x;
  wsh[tid] = w3[tid];
  __syncthreads();
  const int g = blockIdx.x*64 + (tid>>2);
  if (g >= NN) return;
  const int oc = tid&3;
  float s = b3[oc];
  const float* row = &o2[(size_t)g*64];
  #pragma unroll 8
  for (int k=0;k<64;k++) s += row[k]*wsh[k*4+oc];
  out[(size_t)g*4+oc] = s;
}

extern "C" void kernel_launch(void* const* d_in, const int* in_sizes, int n_in,
                              void* d_out, int out_size, void* d_ws, size_t ws_size,
                              hipStream_t stream)
{
  const float* x       = (const float*)d_in[0];
  const int*   ei      = (const int*)d_in[1];
  const float* w_in    = (const float*)d_in[2];
  const float* b_in    = (const float*)d_in[3];
  const float* ln_in_w = (const float*)d_in[4];
  const float* ln_in_b = (const float*)d_in[5];
  const float* Wg      = (const float*)d_in[6];
  const float* a_src   = (const float*)d_in[7];
  const float* a_dst   = (const float*)d_in[8];
  const float* bg      = (const float*)d_in[9];
  const float* lnw     = (const float*)d_in[10];
  const float* lnb     = (const float*)d_in[11];
  const float* w1      = (const float*)d_in[12];
  const float* b1      = (const float*)d_in[13];
  const float* lnow    = (const float*)d_in[14];
  const float* lnob    = (const float*)d_in[15];
  const float* w2      = (const float*)d_in[16];
  const float* b2      = (const float*)d_in[17];
  const float* w3      = (const float*)d_in[18];
  const float* b3      = (const float*)d_in[19];
  float* out = (float*)d_out;

  char* p = (char*)d_ws;
  auto carve = [&](size_t bytes)->void*{
    void* r = (void*)p; p += (bytes + 255) & ~(size_t)255; return r;
  };
  float* h    = (float*)carve((size_t)NN*128*4);
  float* xw   = (float*)carve((size_t)NN*128*4);
  float* als  = (float*)carve((size_t)NN*8*4);
  float* ald  = (float*)carve((size_t)NN*8*4);
  int* offs   = (int*)carve((size_t)(NN+1)*4);
  int* cursor = (int*)carve((size_t)NN*4);
  int* cnt    = (int*)carve((size_t)NN*4);
  int* csrsrc = (int*)carve((size_t)NE*4);
  int* bsum   = (int*)carve(64*4);
  __bf16* pWhi = (__bf16*)carve((size_t)90112*2);
  __bf16* pWlo = (__bf16*)carve((size_t)90112*2);
  float* o2   = h;

  const int* esrc = ei;
  const int* edst = ei + NE;

  // one-time weight repack into MFMA fragment layout (bf16 hi/lo)
  repack_w<<<44, 256, 0, stream>>>(Wg, w1, w2, pWhi, pWlo);

  hipMemsetAsync(cnt, 0, (size_t)NN*4, stream);
  count_edges<<<(NE+255)/256, 256, 0, stream>>>(edst, cnt);
  scan1<<<49, 256, 0, stream>>>(cnt, offs, bsum);
  scan2<<<1, 64, 0, stream>>>(bsum);
  scan3<<<(NN+255)/256, 256, 0, stream>>>(offs, bsum, cursor);
  fill_csr<<<(NE+255)/256, 256, 0, stream>>>(esrc, edst, cursor, csrsrc);

  input_mlp<<<NN/2, 256, 0, stream>>>(x, w_in, b_in, ln_in_w, ln_in_b, h);

  const int GRID = (NN + 63) / 64;   // 1563
  for (int i=0;i<4;i++){
    gemm_mfma<128,false,false,false,true><<<GRID, 256, 0, stream>>>(
        h, pWhi + (size_t)i*16384, pWlo + (size_t)i*16384, nullptr, nullptr, nullptr,
        a_src + i*128, a_dst + i*128, xw, als, ald);
    gat_aggregate<<<NN/4, 256, 0, stream>>>(xw, als, ald, offs, csrsrc,
        bg + i*128, lnw + i*128, lnb + i*128, h);
  }

  gemm_mfma<128,true,true,true,false><<<GRID, 256, 0, stream>>>(
      h, pWhi + 65536, pWlo + 65536, b1, lnow, lnob, nullptr, nullptr, xw, nullptr, nullptr);
  gemm_mfma<64,true,false,true,false><<<GRID, 256, 0, stream>>>(
      xw, pWhi + 81920, pWlo + 81920, b2, nullptr, nullptr, nullptr, nullptr, o2, nullptr, nullptr);
  out_proj<<<(NN+63)/64, 256, 0, stream>>>(o2, w3, b3, out);
}

// Round 12
// 585.845 us; speedup vs baseline: 1.1293x; 1.1293x over previous
//
#include <hip/hip_runtime.h>
#include <hip/hip_bf16.h>

#define NN 100000
#define NE 600000

typedef __bf16 bf16x8 __attribute__((ext_vector_type(8)));
typedef float  f32x4  __attribute__((ext_vector_type(4)));

__device__ __forceinline__ float dot4(float4 a, float4 b){
  return a.x*b.x + a.y*b.y + a.z*b.z + a.w*b.w;
}
// unpack 2 packed bf16 (low = even channel) to floats
__device__ __forceinline__ void bf2f(unsigned v, float& a, float& b){
  union { unsigned u; float f; } ua, ub;
  ua.u = v << 16;
  ub.u = v & 0xFFFF0000u;
  a = ua.f; b = ub.f;
}

// ---------------- CSR build (dst-grouped) ----------------
__global__ void count_edges(const int* __restrict__ dst, int* __restrict__ cnt){
  int e = blockIdx.x*256 + threadIdx.x;
  if (e < NE){
    unsigned d = (unsigned)dst[e];
    if (d < NN) atomicAdd(&cnt[d], 1);
  }
}

__global__ void scan1(const int* __restrict__ cnt, int* __restrict__ offs, int* __restrict__ bsum){
  __shared__ int sh[256];
  const int tid = threadIdx.x;
  const int base = blockIdx.x*2048 + tid*8;
  int pre[8]; int s = 0;
  #pragma unroll
  for (int j=0;j<8;j++){
    int idx = base + j;
    int v = (idx < NN) ? cnt[idx] : 0;
    pre[j] = s; s += v;
  }
  sh[tid] = s;
  __syncthreads();
  for (int d=1; d<256; d<<=1){
    int t = (tid >= d) ? sh[tid-d] : 0;
    __syncthreads();
    sh[tid] += t;
    __syncthreads();
  }
  int off = (tid > 0) ? sh[tid-1] : 0;
  #pragma unroll
  for (int j=0;j<8;j++){
    int idx = base + j;
    if (idx < NN) offs[idx] = off + pre[j];
  }
  if (tid == 255) bsum[blockIdx.x] = sh[255];
}

__global__ void scan2(int* __restrict__ bsum){
  if (threadIdx.x == 0){
    int s = 0;
    for (int i=0;i<49;i++){ int t = bsum[i]; bsum[i] = s; s += t; }
  }
}

__global__ void scan3(int* __restrict__ offs, const int* __restrict__ bsum, int* __restrict__ cursor){
  int i = blockIdx.x*256 + threadIdx.x;
  if (i < NN){
    int v = offs[i] + bsum[i>>11];
    offs[i] = v; cursor[i] = v;
  }
  if (i == 0) offs[NN] = NE;
}

__global__ void fill_csr(const int* __restrict__ src, const int* __restrict__ dst,
                         int* __restrict__ cursor, int* __restrict__ csrsrc){
  int e = blockIdx.x*256 + threadIdx.x;
  if (e < NE){
    unsigned d = (unsigned)dst[e];
    unsigned s = (unsigned)src[e];
    if (d < NN && s < NN){
      int p = atomicAdd(&cursor[d], 1);
      csrsrc[p] = (int)s;
    }
  }
}

// ---------------- weight repack: fp32 W[K][C] -> bf16 hi/lo MFMA fragments ----
__global__ void repack_w(const float* __restrict__ Wg, const float* __restrict__ w1,
                         const float* __restrict__ w2,
                         __bf16* __restrict__ phi, __bf16* __restrict__ plo)
{
  int gid = blockIdx.x*256 + threadIdx.x;
  const float* W; int C; size_t obase; int rem;
  if (gid < 8192)      { W = Wg + (size_t)(gid/2048)*16384; C = 128; obase = (size_t)(gid/2048)*16384; rem = gid % 2048; }
  else if (gid < 10240){ W = w1; C = 128; obase = 65536; rem = gid - 8192; }
  else if (gid < 11264){ W = w2; C = 64;  obase = 81920; rem = gid - 10240; }
  else return;
  const int lane = rem & 63;
  const int tks  = rem >> 6;
  const int ks = tks & 3, t = tks >> 2;
  const int col = t*16 + (lane & 15);
  const int kb  = ks*32 + (lane >> 4)*8;
  const size_t o = obase + (size_t)rem*8;
  #pragma unroll
  for (int j=0;j<8;j++){
    float v = W[(size_t)(kb+j)*C + col];
    __bf16 hb = (__bf16)v;
    phi[o+j] = hb;
    plo[o+j] = (__bf16)(v - (float)hb);
  }
}

// ---------------- input MLP: h = relu(LN(x@w_in+b_in)) ----------------
__global__ __launch_bounds__(256) void input_mlp(const float* __restrict__ x,
    const float* __restrict__ win, const float* __restrict__ b,
    const float* __restrict__ lnw, const float* __restrict__ lnb,
    float* __restrict__ h)
{
  __shared__ float wsh[6*128];
  __shared__ float p2[4][2];
  const int tid = threadIdx.x;
  for (int i=tid;i<768;i+=256) wsh[i] = win[i];
  __syncthreads();
  const int nl = tid>>7, c = tid&127;
  const int n = blockIdx.x*2 + nl;
  float s = b[c];
  #pragma unroll
  for (int k=0;k<6;k++) s += x[n*6+k]*wsh[k*128+c];
  float sum = s, sq = s*s;
  #pragma unroll
  for (int o=32;o>=1;o>>=1){ sum += __shfl_xor(sum,o); sq += __shfl_xor(sq,o); }
  const int wv = tid>>6;
  if ((tid&63)==0){ p2[wv][0]=sum; p2[wv][1]=sq; }
  __syncthreads();
  float ts = p2[nl*2][0]+p2[nl*2+1][0];
  float tq = p2[nl*2][1]+p2[nl*2+1][1];
  float mean = ts*(1.f/128.f);
  float var  = tq*(1.f/128.f) - mean*mean;
  float y = (s-mean)*rsqrtf(var+1e-5f)*lnw[c]+lnb[c];
  h[(size_t)n*128+c] = fmaxf(y, 0.f);
}

// ---------------- MFMA split-bf16 GEMM: Y = act(LN?(X@W + b)), K=128 ----------
// GAT variant stores Y as bf16 (consumed only by gat_aggregate's gather).
template<int C, bool HAS_BIAS, bool DO_LN, bool DO_RELU, bool GAT>
__global__ __launch_bounds__(256) void gemm_mfma(const float* __restrict__ X,
    const __bf16* __restrict__ Bhi, const __bf16* __restrict__ Blo,
    const float* __restrict__ bias,
    const float* __restrict__ lnw, const float* __restrict__ lnb,
    const float* __restrict__ asrc, const float* __restrict__ adst,
    float* __restrict__ Y, __bf16* __restrict__ Yb,
    float* __restrict__ als, float* __restrict__ ald)
{
  constexpr int NT = C/16;
  const int tid = threadIdx.x;
  const int wid = tid >> 6, lane = tid & 63;
  const int lrow = lane & 15, lgrp = lane >> 4;
  const int m0 = (blockIdx.x*4 + wid)*16;

  // A fragments: 4 k-steps, hi/lo
  bf16x8 Ahi[4], Alo[4];
  {
    int row = m0 + lrow; if (row >= NN) row = NN-1;
    const float* Xr = X + (size_t)row*128 + lgrp*8;
    #pragma unroll
    for (int ks=0; ks<4; ks++){
      float4 u0 = *(const float4*)(Xr + ks*32);
      float4 u1 = *(const float4*)(Xr + ks*32 + 4);
      float v[8] = {u0.x,u0.y,u0.z,u0.w,u1.x,u1.y,u1.z,u1.w};
      bf16x8 h8, l8;
      #pragma unroll
      for (int j=0;j<8;j++){
        __bf16 hb = (__bf16)v[j];
        h8[j] = hb;
        l8[j] = (__bf16)(v[j] - (float)hb);
      }
      Ahi[ks] = h8; Alo[ks] = l8;
    }
  }

  f32x4 acc[NT];
  #pragma unroll
  for (int t=0;t<NT;t++){ acc[t] = (f32x4){0.f,0.f,0.f,0.f}; }

  const bf16x8* B8h = (const bf16x8*)Bhi;
  const bf16x8* B8l = (const bf16x8*)Blo;
  #pragma unroll
  for (int t=0;t<NT;t++){
    #pragma unroll
    for (int ks=0;ks<4;ks++){
      bf16x8 bh = B8h[(t*4+ks)*64 + lane];
      bf16x8 bl = B8l[(t*4+ks)*64 + lane];
      acc[t] = __builtin_amdgcn_mfma_f32_16x16x32_bf16(Ahi[ks], bh, acc[t], 0,0,0);
      acc[t] = __builtin_amdgcn_mfma_f32_16x16x32_bf16(Alo[ks], bh, acc[t], 0,0,0);
      acc[t] = __builtin_amdgcn_mfma_f32_16x16x32_bf16(Ahi[ks], bl, acc[t], 0,0,0);
    }
  }

  if constexpr (HAS_BIAS){
    #pragma unroll
    for (int t=0;t<NT;t++){
      float bv = bias[t*16 + lrow];
      #pragma unroll
      for (int i=0;i<4;i++) acc[t][i] += bv;
    }
  }

  if constexpr (GAT){
    #pragma unroll
    for (int t=0;t<NT;t++){
      float av = asrc[t*16 + lrow];
      float dv2 = adst[t*16 + lrow];
      float ps[4], pd[4];
      #pragma unroll
      for (int i=0;i<4;i++){
        int n = m0 + lgrp*4 + i;
        if (n < NN) Yb[(size_t)n*C + t*16 + lrow] = (__bf16)acc[t][i];
        ps[i] = acc[t][i]*av; pd[i] = acc[t][i]*dv2;
      }
      #pragma unroll
      for (int off=1; off<16; off<<=1){
        #pragma unroll
        for (int i=0;i<4;i++){
          ps[i] += __shfl_xor(ps[i], off);
          pd[i] += __shfl_xor(pd[i], off);
        }
      }
      if (lrow == 0){
        #pragma unroll
        for (int i=0;i<4;i++){
          int n = m0 + lgrp*4 + i;
          if (n < NN){ als[n*8 + t] = ps[i]; ald[n*8 + t] = pd[i]; }
        }
      }
    }
  } else {
    if constexpr (DO_LN){
      float s[4] = {0,0,0,0}, q[4] = {0,0,0,0};
      #pragma unroll
      for (int t=0;t<NT;t++){
        #pragma unroll
        for (int i=0;i<4;i++){ s[i] += acc[t][i]; q[i] += acc[t][i]*acc[t][i]; }
      }
      #pragma unroll
      for (int off=1; off<16; off<<=1){
        #pragma unroll
        for (int i=0;i<4;i++){ s[i] += __shfl_xor(s[i], off); q[i] += __shfl_xor(q[i], off); }
      }
      float mean[4], rr[4];
      #pragma unroll
      for (int i=0;i<4;i++){
        mean[i] = s[i]*(1.0f/C);
        float var = q[i]*(1.0f/C) - mean[i]*mean[i];
        rr[i] = rsqrtf(var + 1e-5f);
      }
      #pragma unroll
      for (int t=0;t<NT;t++){
        float lw = lnw[t*16 + lrow], lb = lnb[t*16 + lrow];
        #pragma unroll
        for (int i=0;i<4;i++){
          float v = (acc[t][i]-mean[i])*rr[i]*lw + lb;
          if constexpr (DO_RELU) v = fmaxf(v, 0.f);
          acc[t][i] = v;
        }
      }
    } else if constexpr (DO_RELU){
      #pragma unroll
      for (int t=0;t<NT;t++){
        #pragma unroll
        for (int i=0;i<4;i++) acc[t][i] = fmaxf(acc[t][i], 0.f);
      }
    }
    #pragma unroll
    for (int t=0;t<NT;t++){
      #pragma unroll
      for (int i=0;i<4;i++){
        int n = m0 + lgrp*4 + i;
        if (n < NN) Y[(size_t)n*C + t*16 + lrow] = acc[t][i];
      }
    }
  }
}

// ---------------- per-node softmax + aggregate + LN + residual ----------------
// One wave per node; lane = channel pair (2*lane, 2*lane+1), sharing head
// h = lane>>3. Messages (xw) are bf16-packed: ONE 4 B load + 2 bit-ops per
// edge per lane. Logits stay fp32. No max subtraction (logits O(1)).
// No LDS, no barriers.
__global__ __launch_bounds__(256) void gat_aggregate(
    const __bf16* __restrict__ xw, const float* __restrict__ als, const float* __restrict__ ald,
    const int* __restrict__ offs, const int* __restrict__ csrsrc,
    const float* __restrict__ bg, const float* __restrict__ lnw, const float* __restrict__ lnb,
    float* __restrict__ h)
{
  const int wv = threadIdx.x >> 6, lane = threadIdx.x & 63;
  const int n = blockIdx.x*4 + wv;
  const int hh = lane >> 3;                 // head of channels 2*lane, 2*lane+1
  const float ad = ald[n*8 + hh];

  // self-loop
  float t = als[n*8 + hh] + ad; t = t > 0.f ? t : 0.2f*t;
  float pp = __expf(t);
  float s = pp;
  float xv0, xv1;
  bf2f(*(const unsigned*)(xw + (size_t)n*128 + 2*lane), xv0, xv1);
  float acc0 = pp*xv0, acc1 = pp*xv1;

  const int start = offs[n], end = offs[n+1];
  int e = start;
  for (; e+4 <= end; e += 4){
    int s4[4]; float a[4]; unsigned x2[4];
    #pragma unroll
    for (int j=0;j<4;j++) s4[j] = csrsrc[e+j];
    #pragma unroll
    for (int j=0;j<4;j++){
      a[j]  = als[s4[j]*8 + hh];
      x2[j] = *(const unsigned*)(xw + (size_t)s4[j]*128 + 2*lane);
    }
    #pragma unroll
    for (int j=0;j<4;j++){
      float u = a[j] + ad; u = u > 0.f ? u : 0.2f*u;
      float q = __expf(u);
      s += q;
      float m0, m1; bf2f(x2[j], m0, m1);
      acc0 = fmaf(q, m0, acc0);
      acc1 = fmaf(q, m1, acc1);
    }
  }
  if (e+2 <= end){
    int sA = csrsrc[e], sB = csrsrc[e+1];
    float aA = als[sA*8+hh], aB = als[sB*8+hh];
    unsigned xA = *(const unsigned*)(xw + (size_t)sA*128 + 2*lane);
    unsigned xB = *(const unsigned*)(xw + (size_t)sB*128 + 2*lane);
    float u;
    u = aA+ad; u = u>0.f?u:0.2f*u; float qA = __expf(u);
    u = aB+ad; u = u>0.f?u:0.2f*u; float qB = __expf(u);
    s += qA+qB;
    float mA0, mA1, mB0, mB1; bf2f(xA, mA0, mA1); bf2f(xB, mB0, mB1);
    acc0 = fmaf(qA, mA0, fmaf(qB, mB0, acc0));
    acc1 = fmaf(qA, mA1, fmaf(qB, mB1, acc1));
    e += 2;
  }
  if (e < end){
    int sA = csrsrc[e];
    float aA = als[sA*8+hh];
    unsigned xA = *(const unsigned*)(xw + (size_t)sA*128 + 2*lane);
    float u = aA+ad; u = u>0.f?u:0.2f*u; float qA = __expf(u);
    s += qA;
    float mA0, mA1; bf2f(xA, mA0, mA1);
    acc0 = fmaf(qA, mA0, acc0);
    acc1 = fmaf(qA, mA1, acc1);
  }

  float2 bgv = *(const float2*)(bg + 2*lane);
  float inv = 1.0f/s;
  float val0 = acc0*inv + bgv.x;
  float val1 = acc1*inv + bgv.y;
  // LayerNorm across 128 channels = butterfly over this wave (2 ch/lane)
  float sum = val0+val1, sq = val0*val0 + val1*val1;
  #pragma unroll
  for (int off=32; off>=1; off>>=1){ sum += __shfl_xor(sum,off); sq += __shfl_xor(sq,off); }
  float mean = sum*(1.f/128.f);
  float var  = sq*(1.f/128.f) - mean*mean;
  float rr = rsqrtf(var + 1e-5f);
  float2 lwv = *(const float2*)(lnw + 2*lane);
  float2 lbv = *(const float2*)(lnb + 2*lane);
  float y0 = (val0-mean)*rr*lwv.x + lbv.x;
  float y1 = (val1-mean)*rr*lwv.y + lbv.y;
  float2* hp = (float2*)(h + (size_t)n*128 + 2*lane);
  float2 hv = *hp;
  hv.x += fmaxf(y0, 0.f);
  hv.y += fmaxf(y1, 0.f);
  *hp = hv;
}

// ---------------- final projection: out = o2@w3 + b3 ----------------
__global__ __launch_bounds__(256) void out_proj(const float* __restrict__ o2,
    const float* __restrict__ w3, const float* __restrict__ b3, float* __restrict__ out)
{
  __shared__ float wsh[256];
  const int tid = threadIdx.x;
  wsh[tid] = w3[tid];
  __syncthreads();
  const int g = blockIdx.x*64 + (tid>>2);
  if (g >= NN) return;
  const int oc = tid&3;
  float s = b3[oc];
  const float* row = &o2[(size_t)g*64];
  #pragma unroll 8
  for (int k=0;k<64;k++) s += row[k]*wsh[k*4+oc];
  out[(size_t)g*4+oc] = s;
}

extern "C" void kernel_launch(void* const* d_in, const int* in_sizes, int n_in,
                              void* d_out, int out_size, void* d_ws, size_t ws_size,
                              hipStream_t stream)
{
  const float* x       = (const float*)d_in[0];
  const int*   ei      = (const int*)d_in[1];
  const float* w_in    = (const float*)d_in[2];
  const float* b_in    = (const float*)d_in[3];
  const float* ln_in_w = (const float*)d_in[4];
  const float* ln_in_b = (const float*)d_in[5];
  const float* Wg      = (const float*)d_in[6];
  const float* a_src   = (const float*)d_in[7];
  const float* a_dst   = (const float*)d_in[8];
  const float* bg      = (const float*)d_in[9];
  const float* lnw     = (const float*)d_in[10];
  const float* lnb     = (const float*)d_in[11];
  const float* w1      = (const float*)d_in[12];
  const float* b1      = (const float*)d_in[13];
  const float* lnow    = (const float*)d_in[14];
  const float* lnob    = (const float*)d_in[15];
  const float* w2      = (const float*)d_in[16];
  const float* b2      = (const float*)d_in[17];
  const float* w3      = (const float*)d_in[18];
  const float* b3      = (const float*)d_in[19];
  float* out = (float*)d_out;

  char* p = (char*)d_ws;
  auto carve = [&](size_t bytes)->void*{
    void* r = (void*)p; p += (bytes + 255) & ~(size_t)255; return r;
  };
  float* h    = (float*)carve((size_t)NN*128*4);
  float* xw   = (float*)carve((size_t)NN*128*4);   // fp32 o1 output
  __bf16* xwb = (__bf16*)carve((size_t)NN*128*2);  // bf16 GAT messages
  float* als  = (float*)carve((size_t)NN*8*4);
  float* ald  = (float*)carve((size_t)NN*8*4);
  int* offs   = (int*)carve((size_t)(NN+1)*4);
  int* cursor = (int*)carve((size_t)NN*4);
  int* cnt    = (int*)carve((size_t)NN*4);
  int* csrsrc = (int*)carve((size_t)NE*4);
  int* bsum   = (int*)carve(64*4);
  __bf16* pWhi = (__bf16*)carve((size_t)90112*2);
  __bf16* pWlo = (__bf16*)carve((size_t)90112*2);
  float* o2   = h;

  const int* esrc = ei;
  const int* edst = ei + NE;

  // one-time weight repack into MFMA fragment layout (bf16 hi/lo)
  repack_w<<<44, 256, 0, stream>>>(Wg, w1, w2, pWhi, pWlo);

  hipMemsetAsync(cnt, 0, (size_t)NN*4, stream);
  count_edges<<<(NE+255)/256, 256, 0, stream>>>(edst, cnt);
  scan1<<<49, 256, 0, stream>>>(cnt, offs, bsum);
  scan2<<<1, 64, 0, stream>>>(bsum);
  scan3<<<(NN+255)/256, 256, 0, stream>>>(offs, bsum, cursor);
  fill_csr<<<(NE+255)/256, 256, 0, stream>>>(esrc, edst, cursor, csrsrc);

  input_mlp<<<NN/2, 256, 0, stream>>>(x, w_in, b_in, ln_in_w, ln_in_b, h);

  const int GRID = (NN + 63) / 64;   // 1563
  for (int i=0;i<4;i++){
    gemm_mfma<128,false,false,false,true><<<GRID, 256, 0, stream>>>(
        h, pWhi + (size_t)i*16384, pWlo + (size_t)i*16384, nullptr, nullptr, nullptr,
        a_src + i*128, a_dst + i*128, nullptr, xwb, als, ald);
    gat_aggregate<<<NN/4, 256, 0, stream>>>(xwb, als, ald, offs, csrsrc,
        bg + i*128, lnw + i*128, lnb + i*128, h);
  }

  gemm_mfma<128,true,true,true,false><<<GRID, 256, 0, stream>>>(
      h, pWhi + 65536, pWlo + 65536, b1, lnow, lnob, nullptr, nullptr, xw, nullptr, nullptr, nullptr);
  gemm_mfma<64,true,false,true,false><<<GRID, 256, 0, stream>>>(
      xw, pWhi + 81920, pWlo + 81920, b2, nullptr, nullptr, nullptr, nullptr, o2, nullptr, nullptr, nullptr);
  out_proj<<<(NN+63)/64, 256, 0, stream>>>(o2, w3, b3, out);
}

// Round 13
// 522.627 us; speedup vs baseline: 1.2660x; 1.1210x over previous
//
#include <hip/hip_runtime.h>
#include <hip/hip_bf16.h>

#define NN 100000
#define NE 600000

typedef __bf16 bf16x8 __attribute__((ext_vector_type(8)));
typedef float  f32x4  __attribute__((ext_vector_type(4)));

__device__ __forceinline__ float dot4(float4 a, float4 b){
  return a.x*b.x + a.y*b.y + a.z*b.z + a.w*b.w;
}
// unpack 2 packed bf16 (low = even channel) to floats
__device__ __forceinline__ void bf2f(unsigned v, float& a, float& b){
  union { unsigned u; float f; } ua, ub;
  ua.u = v << 16;
  ub.u = v & 0xFFFF0000u;
  a = ua.f; b = ub.f;
}

// ---------------- CSR build (dst-grouped) ----------------
__global__ void count_edges(const int* __restrict__ dst, int* __restrict__ cnt){
  int e = blockIdx.x*256 + threadIdx.x;
  if (e < NE){
    unsigned d = (unsigned)dst[e];
    if (d < NN) atomicAdd(&cnt[d], 1);
  }
}

__global__ void scan1(const int* __restrict__ cnt, int* __restrict__ offs, int* __restrict__ bsum){
  __shared__ int sh[256];
  const int tid = threadIdx.x;
  const int base = blockIdx.x*2048 + tid*8;
  int pre[8]; int s = 0;
  #pragma unroll
  for (int j=0;j<8;j++){
    int idx = base + j;
    int v = (idx < NN) ? cnt[idx] : 0;
    pre[j] = s; s += v;
  }
  sh[tid] = s;
  __syncthreads();
  for (int d=1; d<256; d<<=1){
    int t = (tid >= d) ? sh[tid-d] : 0;
    __syncthreads();
    sh[tid] += t;
    __syncthreads();
  }
  int off = (tid > 0) ? sh[tid-1] : 0;
  #pragma unroll
  for (int j=0;j<8;j++){
    int idx = base + j;
    if (idx < NN) offs[idx] = off + pre[j];
  }
  if (tid == 255) bsum[blockIdx.x] = sh[255];
}

__global__ void scan2(int* __restrict__ bsum){
  if (threadIdx.x == 0){
    int s = 0;
    for (int i=0;i<49;i++){ int t = bsum[i]; bsum[i] = s; s += t; }
  }
}

__global__ void scan3(int* __restrict__ offs, const int* __restrict__ bsum, int* __restrict__ cursor){
  int i = blockIdx.x*256 + threadIdx.x;
  if (i < NN){
    int v = offs[i] + bsum[i>>11];
    offs[i] = v; cursor[i] = v;
  }
  if (i == 0) offs[NN] = NE;
}

__global__ void fill_csr(const int* __restrict__ src, const int* __restrict__ dst,
                         int* __restrict__ cursor, int* __restrict__ csrsrc){
  int e = blockIdx.x*256 + threadIdx.x;
  if (e < NE){
    unsigned d = (unsigned)dst[e];
    unsigned s = (unsigned)src[e];
    if (d < NN && s < NN){
      int p = atomicAdd(&cursor[d], 1);
      csrsrc[p] = (int)s;
    }
  }
}

// ---------------- weight repack: fp32 W[K][C] -> bf16 hi/lo MFMA fragments ----
__global__ void repack_w(const float* __restrict__ Wg, const float* __restrict__ w1,
                         const float* __restrict__ w2,
                         __bf16* __restrict__ phi, __bf16* __restrict__ plo)
{
  int gid = blockIdx.x*256 + threadIdx.x;
  const float* W; int C; size_t obase; int rem;
  if (gid < 8192)      { W = Wg + (size_t)(gid/2048)*16384; C = 128; obase = (size_t)(gid/2048)*16384; rem = gid % 2048; }
  else if (gid < 10240){ W = w1; C = 128; obase = 65536; rem = gid - 8192; }
  else if (gid < 11264){ W = w2; C = 64;  obase = 81920; rem = gid - 10240; }
  else return;
  const int lane = rem & 63;
  const int tks  = rem >> 6;
  const int ks = tks & 3, t = tks >> 2;
  const int col = t*16 + (lane & 15);
  const int kb  = ks*32 + (lane >> 4)*8;
  const size_t o = obase + (size_t)rem*8;
  #pragma unroll
  for (int j=0;j<8;j++){
    float v = W[(size_t)(kb+j)*C + col];
    __bf16 hb = (__bf16)v;
    phi[o+j] = hb;
    plo[o+j] = (__bf16)(v - (float)hb);
  }
}

// ---------------- input MLP: h = relu(LN(x@w_in+b_in)) ----------------
// 4 channels/thread (float4 I/O), 32-lane LN groups, 8 nodes/block.
// W (3 KB) read straight from L2; x row is a per-group broadcast.
__global__ __launch_bounds__(256) void input_mlp(const float* __restrict__ x,
    const float* __restrict__ win, const float* __restrict__ b,
    const float* __restrict__ lnw, const float* __restrict__ lnb,
    float* __restrict__ h)
{
  const int tid = threadIdx.x;
  const int g = tid >> 5, l = tid & 31;
  const int n = blockIdx.x*8 + g;
  const float4* W4 = (const float4*)win;   // W4[k*32 + l] = win[k][4l..4l+3]
  float xr[6];
  #pragma unroll
  for (int k=0;k<6;k++) xr[k] = x[n*6+k];
  float4 s = ((const float4*)b)[l];
  #pragma unroll
  for (int k=0;k<6;k++){
    float4 w = W4[k*32 + l];
    s.x = fmaf(xr[k], w.x, s.x);
    s.y = fmaf(xr[k], w.y, s.y);
    s.z = fmaf(xr[k], w.z, s.z);
    s.w = fmaf(xr[k], w.w, s.w);
  }
  float sum = s.x+s.y+s.z+s.w;
  float sq  = dot4(s,s);
  #pragma unroll
  for (int o=16;o>=1;o>>=1){ sum += __shfl_xor(sum,o); sq += __shfl_xor(sq,o); }
  float mean = sum*(1.f/128.f);
  float var  = sq*(1.f/128.f) - mean*mean;
  float rr = rsqrtf(var + 1e-5f);
  float4 lw = ((const float4*)lnw)[l];
  float4 lb = ((const float4*)lnb)[l];
  float4 y;
  y.x = fmaxf((s.x-mean)*rr*lw.x + lb.x, 0.f);
  y.y = fmaxf((s.y-mean)*rr*lw.y + lb.y, 0.f);
  y.z = fmaxf((s.z-mean)*rr*lw.z + lb.z, 0.f);
  y.w = fmaxf((s.w-mean)*rr*lw.w + lb.w, 0.f);
  ((float4*)(h + (size_t)n*128))[l] = y;
}

// ---------------- MFMA split-bf16 GEMM: Y = act(LN?(X@W + b)), K=128 ----------
// ks-outer / t-inner schedule: per ks, all NT bh frags are loaded, then three
// NT-wide MFMA passes (Ahi*bh, Alo*bh, Ahi*bl) -> dependent uses of acc[t]
// are NT instructions apart (was a 12-deep chain -> latency-bound, MfmaUtil 5%).
template<int C, bool HAS_BIAS, bool DO_LN, bool DO_RELU, bool GAT>
__global__ __launch_bounds__(256) void gemm_mfma(const float* __restrict__ X,
    const __bf16* __restrict__ Bhi, const __bf16* __restrict__ Blo,
    const float* __restrict__ bias,
    const float* __restrict__ lnw, const float* __restrict__ lnb,
    const float* __restrict__ asrc, const float* __restrict__ adst,
    float* __restrict__ Y, __bf16* __restrict__ Yb,
    float* __restrict__ als, float* __restrict__ ald)
{
  constexpr int NT = C/16;
  const int tid = threadIdx.x;
  const int wid = tid >> 6, lane = tid & 63;
  const int lrow = lane & 15, lgrp = lane >> 4;
  const int m0 = (blockIdx.x*4 + wid)*16;

  // A fragments: 4 k-steps, hi/lo
  bf16x8 Ahi[4], Alo[4];
  {
    int row = m0 + lrow; if (row >= NN) row = NN-1;
    const float* Xr = X + (size_t)row*128 + lgrp*8;
    #pragma unroll
    for (int ks=0; ks<4; ks++){
      float4 u0 = *(const float4*)(Xr + ks*32);
      float4 u1 = *(const float4*)(Xr + ks*32 + 4);
      float v[8] = {u0.x,u0.y,u0.z,u0.w,u1.x,u1.y,u1.z,u1.w};
      bf16x8 h8, l8;
      #pragma unroll
      for (int j=0;j<8;j++){
        __bf16 hb = (__bf16)v[j];
        h8[j] = hb;
        l8[j] = (__bf16)(v[j] - (float)hb);
      }
      Ahi[ks] = h8; Alo[ks] = l8;
    }
  }

  f32x4 acc[NT];
  #pragma unroll
  for (int t=0;t<NT;t++){ acc[t] = (f32x4){0.f,0.f,0.f,0.f}; }

  const bf16x8* B8h = (const bf16x8*)Bhi;
  const bf16x8* B8l = (const bf16x8*)Blo;
  #pragma unroll
  for (int ks=0;ks<4;ks++){
    bf16x8 bh[NT];
    #pragma unroll
    for (int t=0;t<NT;t++) bh[t] = B8h[(t*4+ks)*64 + lane];
    #pragma unroll
    for (int t=0;t<NT;t++)
      acc[t] = __builtin_amdgcn_mfma_f32_16x16x32_bf16(Ahi[ks], bh[t], acc[t], 0,0,0);
    #pragma unroll
    for (int t=0;t<NT;t++)
      acc[t] = __builtin_amdgcn_mfma_f32_16x16x32_bf16(Alo[ks], bh[t], acc[t], 0,0,0);
    #pragma unroll
    for (int t=0;t<NT;t++){
      bf16x8 bl = B8l[(t*4+ks)*64 + lane];
      acc[t] = __builtin_amdgcn_mfma_f32_16x16x32_bf16(Ahi[ks], bl, acc[t], 0,0,0);
    }
  }

  if constexpr (HAS_BIAS){
    #pragma unroll
    for (int t=0;t<NT;t++){
      float bv = bias[t*16 + lrow];
      #pragma unroll
      for (int i=0;i<4;i++) acc[t][i] += bv;
    }
  }

  if constexpr (GAT){
    #pragma unroll
    for (int t=0;t<NT;t++){
      float av = asrc[t*16 + lrow];
      float dv2 = adst[t*16 + lrow];
      float ps[4], pd[4];
      #pragma unroll
      for (int i=0;i<4;i++){
        int n = m0 + lgrp*4 + i;
        if (n < NN) Yb[(size_t)n*C + t*16 + lrow] = (__bf16)acc[t][i];
        ps[i] = acc[t][i]*av; pd[i] = acc[t][i]*dv2;
      }
      #pragma unroll
      for (int off=1; off<16; off<<=1){
        #pragma unroll
        for (int i=0;i<4;i++){
          ps[i] += __shfl_xor(ps[i], off);
          pd[i] += __shfl_xor(pd[i], off);
        }
      }
      if (lrow == 0){
        #pragma unroll
        for (int i=0;i<4;i++){
          int n = m0 + lgrp*4 + i;
          if (n < NN){ als[n*8 + t] = ps[i]; ald[n*8 + t] = pd[i]; }
        }
      }
    }
  } else {
    if constexpr (DO_LN){
      float s[4] = {0,0,0,0}, q[4] = {0,0,0,0};
      #pragma unroll
      for (int t=0;t<NT;t++){
        #pragma unroll
        for (int i=0;i<4;i++){ s[i] += acc[t][i]; q[i] += acc[t][i]*acc[t][i]; }
      }
      #pragma unroll
      for (int off=1; off<16; off<<=1){
        #pragma unroll
        for (int i=0;i<4;i++){ s[i] += __shfl_xor(s[i], off); q[i] += __shfl_xor(q[i], off); }
      }
      float mean[4], rr[4];
      #pragma unroll
      for (int i=0;i<4;i++){
        mean[i] = s[i]*(1.0f/C);
        float var = q[i]*(1.0f/C) - mean[i]*mean[i];
        rr[i] = rsqrtf(var + 1e-5f);
      }
      #pragma unroll
      for (int t=0;t<NT;t++){
        float lw = lnw[t*16 + lrow], lb = lnb[t*16 + lrow];
        #pragma unroll
        for (int i=0;i<4;i++){
          float v = (acc[t][i]-mean[i])*rr[i]*lw + lb;
          if constexpr (DO_RELU) v = fmaxf(v, 0.f);
          acc[t][i] = v;
        }
      }
    } else if constexpr (DO_RELU){
      #pragma unroll
      for (int t=0;t<NT;t++){
        #pragma unroll
        for (int i=0;i<4;i++) acc[t][i] = fmaxf(acc[t][i], 0.f);
      }
    }
    #pragma unroll
    for (int t=0;t<NT;t++){
      #pragma unroll
      for (int i=0;i<4;i++){
        int n = m0 + lgrp*4 + i;
        if (n < NN) Y[(size_t)n*C + t*16 + lrow] = acc[t][i];
      }
    }
  }
}

// ---------------- per-node softmax + aggregate + LN + residual ----------------
// One wave per node; lane = channel pair (2*lane, 2*lane+1), sharing head
// h = lane>>3. Messages (xw) are bf16-packed: ONE 4 B load + 2 bit-ops per
// edge per lane. Logits stay fp32. No max subtraction (logits O(1)).
// No LDS, no barriers.
__global__ __launch_bounds__(256) void gat_aggregate(
    const __bf16* __restrict__ xw, const float* __restrict__ als, const float* __restrict__ ald,
    const int* __restrict__ offs, const int* __restrict__ csrsrc,
    const float* __restrict__ bg, const float* __restrict__ lnw, const float* __restrict__ lnb,
    float* __restrict__ h)
{
  const int wv = threadIdx.x >> 6, lane = threadIdx.x & 63;
  const int n = blockIdx.x*4 + wv;
  const int hh = lane >> 3;                 // head of channels 2*lane, 2*lane+1
  const float ad = ald[n*8 + hh];

  // self-loop
  float t = als[n*8 + hh] + ad; t = t > 0.f ? t : 0.2f*t;
  float pp = __expf(t);
  float s = pp;
  float xv0, xv1;
  bf2f(*(const unsigned*)(xw + (size_t)n*128 + 2*lane), xv0, xv1);
  float acc0 = pp*xv0, acc1 = pp*xv1;

  const int start = offs[n], end = offs[n+1];
  int e = start;
  for (; e+4 <= end; e += 4){
    int s4[4]; float a[4]; unsigned x2[4];
    #pragma unroll
    for (int j=0;j<4;j++) s4[j] = csrsrc[e+j];
    #pragma unroll
    for (int j=0;j<4;j++){
      a[j]  = als[s4[j]*8 + hh];
      x2[j] = *(const unsigned*)(xw + (size_t)s4[j]*128 + 2*lane);
    }
    #pragma unroll
    for (int j=0;j<4;j++){
      float u = a[j] + ad; u = u > 0.f ? u : 0.2f*u;
      float q = __expf(u);
      s += q;
      float m0, m1; bf2f(x2[j], m0, m1);
      acc0 = fmaf(q, m0, acc0);
      acc1 = fmaf(q, m1, acc1);
    }
  }
  if (e+2 <= end){
    int sA = csrsrc[e], sB = csrsrc[e+1];
    float aA = als[sA*8+hh], aB = als[sB*8+hh];
    unsigned xA = *(const unsigned*)(xw + (size_t)sA*128 + 2*lane);
    unsigned xB = *(const unsigned*)(xw + (size_t)sB*128 + 2*lane);
    float u;
    u = aA+ad; u = u>0.f?u:0.2f*u; float qA = __expf(u);
    u = aB+ad; u = u>0.f?u:0.2f*u; float qB = __expf(u);
    s += qA+qB;
    float mA0, mA1, mB0, mB1; bf2f(xA, mA0, mA1); bf2f(xB, mB0, mB1);
    acc0 = fmaf(qA, mA0, fmaf(qB, mB0, acc0));
    acc1 = fmaf(qA, mA1, fmaf(qB, mB1, acc1));
    e += 2;
  }
  if (e < end){
    int sA = csrsrc[e];
    float aA = als[sA*8+hh];
    unsigned xA = *(const unsigned*)(xw + (size_t)sA*128 + 2*lane);
    float u = aA+ad; u = u>0.f?u:0.2f*u; float qA = __expf(u);
    s += qA;
    float mA0, mA1; bf2f(xA, mA0, mA1);
    acc0 = fmaf(qA, mA0, acc0);
    acc1 = fmaf(qA, mA1, acc1);
  }

  float2 bgv = *(const float2*)(bg + 2*lane);
  float inv = 1.0f/s;
  float val0 = acc0*inv + bgv.x;
  float val1 = acc1*inv + bgv.y;
  // LayerNorm across 128 channels = butterfly over this wave (2 ch/lane)
  float sum = val0+val1, sq = val0*val0 + val1*val1;
  #pragma unroll
  for (int off=32; off>=1; off>>=1){ sum += __shfl_xor(sum,off); sq += __shfl_xor(sq,off); }
  float mean = sum*(1.f/128.f);
  float var  = sq*(1.f/128.f) - mean*mean;
  float rr = rsqrtf(var + 1e-5f);
  float2 lwv = *(const float2*)(lnw + 2*lane);
  float2 lbv = *(const float2*)(lnb + 2*lane);
  float y0 = (val0-mean)*rr*lwv.x + lbv.x;
  float y1 = (val1-mean)*rr*lwv.y + lbv.y;
  float2* hp = (float2*)(h + (size_t)n*128 + 2*lane);
  float2 hv = *hp;
  hv.x += fmaxf(y0, 0.f);
  hv.y += fmaxf(y1, 0.f);
  *hp = hv;
}

// ---------------- final projection: out = o2@w3 + b3 ----------------
__global__ __launch_bounds__(256) void out_proj(const float* __restrict__ o2,
    const float* __restrict__ w3, const float* __restrict__ b3, float* __restrict__ out)
{
  __shared__ float wsh[256];
  const int tid = threadIdx.x;
  wsh[tid] = w3[tid];
  __syncthreads();
  const int g = blockIdx.x*64 + (tid>>2);
  if (g >= NN) return;
  const int oc = tid&3;
  float s = b3[oc];
  const float* row = &o2[(size_t)g*64];
  #pragma unroll 8
  for (int k=0;k<64;k++) s += row[k]*wsh[k*4+oc];
  out[(size_t)g*4+oc] = s;
}

extern "C" void kernel_launch(void* const* d_in, const int* in_sizes, int n_in,
                              void* d_out, int out_size, void* d_ws, size_t ws_size,
                              hipStream_t stream)
{
  const float* x       = (const float*)d_in[0];
  const int*   ei      = (const int*)d_in[1];
  const float* w_in    = (const float*)d_in[2];
  const float* b_in    = (const float*)d_in[3];
  const float* ln_in_w = (const float*)d_in[4];
  const float* ln_in_b = (const float*)d_in[5];
  const float* Wg      = (const float*)d_in[6];
  const float* a_src   = (const float*)d_in[7];
  const float* a_dst   = (const float*)d_in[8];
  const float* bg      = (const float*)d_in[9];
  const float* lnw     = (const float*)d_in[10];
  const float* lnb     = (const float*)d_in[11];
  const float* w1      = (const float*)d_in[12];
  const float* b1      = (const float*)d_in[13];
  const float* lnow    = (const float*)d_in[14];
  const float* lnob    = (const float*)d_in[15];
  const float* w2      = (const float*)d_in[16];
  const float* b2      = (const float*)d_in[17];
  const float* w3      = (const float*)d_in[18];
  const float* b3      = (const float*)d_in[19];
  float* out = (float*)d_out;

  char* p = (char*)d_ws;
  auto carve = [&](size_t bytes)->void*{
    void* r = (void*)p; p += (bytes + 255) & ~(size_t)255; return r;
  };
  float* h    = (float*)carve((size_t)NN*128*4);
  float* xw   = (float*)carve((size_t)NN*128*4);   // fp32 o1 output
  __bf16* xwb = (__bf16*)carve((size_t)NN*128*2);  // bf16 GAT messages
  float* als  = (float*)carve((size_t)NN*8*4);
  float* ald  = (float*)carve((size_t)NN*8*4);
  int* offs   = (int*)carve((size_t)(NN+1)*4);
  int* cursor = (int*)carve((size_t)NN*4);
  int* cnt    = (int*)carve((size_t)NN*4);
  int* csrsrc = (int*)carve((size_t)NE*4);
  int* bsum   = (int*)carve(64*4);
  __bf16* pWhi = (__bf16*)carve((size_t)90112*2);
  __bf16* pWlo = (__bf16*)carve((size_t)90112*2);
  float* o2   = h;

  const int* esrc = ei;
  const int* edst = ei + NE;

  // one-time weight repack into MFMA fragment layout (bf16 hi/lo)
  repack_w<<<44, 256, 0, stream>>>(Wg, w1, w2, pWhi, pWlo);

  hipMemsetAsync(cnt, 0, (size_t)NN*4, stream);
  count_edges<<<(NE+255)/256, 256, 0, stream>>>(edst, cnt);
  scan1<<<49, 256, 0, stream>>>(cnt, offs, bsum);
  scan2<<<1, 64, 0, stream>>>(bsum);
  scan3<<<(NN+255)/256, 256, 0, stream>>>(offs, bsum, cursor);
  fill_csr<<<(NE+255)/256, 256, 0, stream>>>(esrc, edst, cursor, csrsrc);

  input_mlp<<<NN/8, 256, 0, stream>>>(x, w_in, b_in, ln_in_w, ln_in_b, h);

  const int GRID = (NN + 63) / 64;   // 1563
  for (int i=0;i<4;i++){
    gemm_mfma<128,false,false,false,true><<<GRID, 256, 0, stream>>>(
        h, pWhi + (size_t)i*16384, pWlo + (size_t)i*16384, nullptr, nullptr, nullptr,
        a_src + i*128, a_dst + i*128, nullptr, xwb, als, ald);
    gat_aggregate<<<NN/4, 256, 0, stream>>>(xwb, als, ald, offs, csrsrc,
        bg + i*128, lnw + i*128, lnb + i*128, h);
  }

  gemm_mfma<128,true,true,true,false><<<GRID, 256, 0, stream>>>(
      h, pWhi + 65536, pWlo + 65536, b1, lnow, lnob, nullptr, nullptr, xw, nullptr, nullptr, nullptr);
  gemm_mfma<64,true,false,true,false><<<GRID, 256, 0, stream>>>(
      xw, pWhi + 81920, pWlo + 81920, b2, nullptr, nullptr, nullptr, nullptr, o2, nullptr, nullptr, nullptr);
  out_proj<<<(NN+63)/64, 256, 0, stream>>>(o2, w3, b3, out);
}